// Round 1
// baseline (377.116 us; speedup 1.0000x reference)
//
#include <hip/hip_runtime.h>

// PoolingRetriever collapses: softmax over a size-1 axis == 1.0, so
//   out = (x @ Wv.T + bv) @ Wo.T + bo
// x: (65536,768) f32. Wv: (64,768). Wo: (768,64). out: (65536,768) f32.
//
// Barrier-light design: weights pre-packed (pack_weights) into MFMA
// B-fragment order as bf16 in d_ws; every wave loads fragments directly from
// global (L2-resident, 16B/lane). x A-fragments loaded straight from global
// (8 consecutive f32 per lane -> cvt bf16). One __syncthreads total
// (V C->A layout LDS transpose, per-wave slice).
//
// R1 change vs 369us baseline: kernel was latency-bound (Occupancy 19%,
// MfmaUtil 4%, VALUBusy 6%, HBM 2.5/6.3 TB/s) with only 2048 waves in the
// whole grid (2/SIMD). Halve rows-per-wave (32->16) and go 4 waves/block:
// 4096 waves (4/SIMD), plus unroll-4 on the k-loop to keep 8 x-loads in
// flight per wave. Fragment layouts identical to the verified kernel.

#define DIM 768
#define NB  64
#define KC  (DIM / 32)          // 24 k-chunks of 32
#define RPW 16                  // rows per wave (one 16-row MFMA strip)
#define WPB 4                   // waves per block (256 threads)
#define RPB (RPW * WPB)         // 64 rows per block
#define WV_ELEMS (NB * DIM)     // 49152 per weight matrix

typedef __attribute__((ext_vector_type(8))) short short8;
typedef __attribute__((ext_vector_type(4))) float f32x4;

__device__ __forceinline__ unsigned short f2bf(float f) {
    union { float f; unsigned int u; } v; v.f = f;
    return (unsigned short)((v.u + 0x7fffu + ((v.u >> 16) & 1u)) >> 16);
}

__device__ __forceinline__ short8 pack_bf8(float4 lo, float4 hi) {
    short8 r;
    r[0] = (short)f2bf(lo.x); r[1] = (short)f2bf(lo.y);
    r[2] = (short)f2bf(lo.z); r[3] = (short)f2bf(lo.w);
    r[4] = (short)f2bf(hi.x); r[5] = (short)f2bf(hi.y);
    r[6] = (short)f2bf(hi.z); r[7] = (short)f2bf(hi.w);
    return r;
}

// Pack Wv and Wo (f32, row-major) into bf16 MFMA B-fragment order.
// pWv frag (kc,t): element idx ((kc*4+t)*64 + lane)*8 + j holds
//   Wv[n = t*16 + (lane&15)][k = kc*32 + (lane>>4)*8 + j]
// pWo frag (tile,h): element idx ((tile*2+h)*64 + lane)*8 + j holds
//   Wo[n = tile*16 + (lane&15)][jd = h*32 + (lane>>4)*8 + j]
__global__ void pack_weights(const float* __restrict__ Wv, const float* __restrict__ Wo,
                             unsigned short* __restrict__ pWv, unsigned short* __restrict__ pWo) {
    int e = blockIdx.x * 256 + threadIdx.x;      // 0 .. 2*49152-1
    int which = (e >= WV_ELEMS) ? 1 : 0;
    int idx = which ? e - WV_ELEMS : e;
    int frag = idx >> 9;                          // per-frag: 64 lanes * 8 elems
    int lane = (idx >> 3) & 63;
    int j = idx & 7;
    int lm = lane & 15, lq = lane >> 4;
    float v;
    if (!which) {
        int kc = frag >> 2, t = frag & 3;
        v = Wv[(t * 16 + lm) * DIM + kc * 32 + lq * 8 + j];
    } else {
        int tile = frag >> 1, h = frag & 1;
        v = Wo[(tile * 16 + lm) * NB + h * 32 + lq * 8 + j];
    }
    (which ? pWo : pWv)[idx] = f2bf(v);
}

__global__ __launch_bounds__(256, 4)
void pr_main(const float* __restrict__ x,
             const unsigned short* __restrict__ pWv, const float* __restrict__ bv,
             const unsigned short* __restrict__ pWo, const float* __restrict__ bo,
             float* __restrict__ out)
{
    __shared__ unsigned short sV[WPB][RPW][72];   // 4*16*72*2 = 9216 B

    const int tid  = threadIdx.x;
    const int wave = tid >> 6;
    const int lane = tid & 63;
    const int lq   = lane >> 4;
    const int lm   = lane & 15;
    const long row0 = (long)blockIdx.x * RPB + wave * RPW;

    // ---------------- Phase 1: V = x @ Wv.T (per wave: 16 rows x 64 n) ----
    f32x4 accV[4];
    #pragma unroll
    for (int t = 0; t < 4; ++t) accV[t] = (f32x4){0.f, 0.f, 0.f, 0.f};

    const float* xb = x + (row0 + lm) * DIM + lq * 8;
    const short8* wv = (const short8*)pWv + lane;   // + frag*64

    #pragma unroll 4
    for (int kc = 0; kc < KC; ++kc) {
        const float4 al = *(const float4*)(xb + kc * 32);
        const float4 ah = *(const float4*)(xb + kc * 32 + 4);
        const short8 a = pack_bf8(al, ah);
        #pragma unroll
        for (int t = 0; t < 4; ++t) {
            const short8 b = wv[(kc * 4 + t) * 64];
            accV[t] = __builtin_amdgcn_mfma_f32_16x16x32_bf16(a, b, accV[t], 0, 0, 0);
        }
    }

    // ------- Phase 1.5: V + bv -> LDS (bf16), C-layout -> A-layout --------
    #pragma unroll
    for (int t = 0; t < 4; ++t) {
        const float bvn = bv[t * 16 + lm];
        #pragma unroll
        for (int r = 0; r < 4; ++r) {
            sV[wave][lq * 4 + r][t * 16 + lm] = f2bf(accV[t][r] + bvn);
        }
    }
    __syncthreads();
    short8 aV0 = *(const short8*)&sV[wave][lm][lq * 8];
    short8 aV1 = *(const short8*)&sV[wave][lm][32 + lq * 8];

    // ---------------- Phase 2: out = V @ Wo.T + bo ------------------------
    const short8* wo = (const short8*)pWo + lane;   // + frag*64
    for (int cc = 0; cc < 12; ++cc) {
        f32x4 acc[4];
        #pragma unroll
        for (int t = 0; t < 4; ++t) acc[t] = (f32x4){0.f, 0.f, 0.f, 0.f};

        #pragma unroll
        for (int t = 0; t < 4; ++t) {
            const int tile = cc * 4 + t;
            const short8 b0 = wo[(tile * 2 + 0) * 64];
            const short8 b1 = wo[(tile * 2 + 1) * 64];
            acc[t] = __builtin_amdgcn_mfma_f32_16x16x32_bf16(aV0, b0, acc[t], 0, 0, 0);
            acc[t] = __builtin_amdgcn_mfma_f32_16x16x32_bf16(aV1, b1, acc[t], 0, 0, 0);
        }

        #pragma unroll
        for (int t = 0; t < 4; ++t) {
            const int col = cc * 64 + t * 16 + lm;
            const float boc = bo[col];
            #pragma unroll
            for (int r = 0; r < 4; ++r) {
                out[(row0 + lq * 4 + r) * DIM + col] = acc[t][r] + boc;
            }
        }
    }
}

extern "C" void kernel_launch(void* const* d_in, const int* in_sizes, int n_in,
                              void* d_out, int out_size, void* d_ws, size_t ws_size,
                              hipStream_t stream) {
    const float* x  = (const float*)d_in[0];
    // d_in[1..5] = q_state, Wq, bq, Wk, bk — mathematically dead: softmax over
    // the size-1 sequence axis is identically 1, so out depends only on v path.
    const float* Wv = (const float*)d_in[6];
    const float* bv = (const float*)d_in[7];
    const float* Wo = (const float*)d_in[8];
    const float* bo = (const float*)d_in[9];
    float* out = (float*)d_out;

    unsigned short* pWv = (unsigned short*)d_ws;          // 96 KB
    unsigned short* pWo = pWv + WV_ELEMS;                 // 96 KB

    pack_weights<<<dim3(2 * WV_ELEMS / 256), dim3(256), 0, stream>>>(Wv, Wo, pWv, pWo);

    const int Bn = in_sizes[0] / DIM;                     // 65536
    pr_main<<<dim3(Bn / RPB), dim3(256), 0, stream>>>(x, pWv, bv, pWo, bo, out);
}